// Round 1
// baseline (1622.768 us; speedup 1.0000x reference)
//
#include <hip/hip_runtime.h>
#include <math.h>

namespace {

constexpr int S = 2048;
constexpr int B = 4;
constexpr int H = 8;

// ---------------------------------------------------------------------------
// GEMM: C[M=8192, N] = A[M,512] @ W[N,512]^T   (both row-major, K contiguous)
// 64x64 tile, TK=16, 256 threads, 4x4 micro-tile.
// MODE 0: scatter into Q'(dims 0..63), K'(0..63), V   (from x @ Wqkv^T)
// MODE 1: scatter into Q'(dims 64..127), K'(64..127)  (from PE @ UqUk^T)
// MODE 2: plain row-major store (out = vals @ Wo^T)
// ---------------------------------------------------------------------------
template<int MODE>
__global__ __launch_bounds__(256)
void gemm_bt(const float* __restrict__ A, const float* __restrict__ W,
             float* __restrict__ o0, float* __restrict__ o1, float* __restrict__ o2)
{
    __shared__ float As[16][68];   // k-major, pad 68 -> 2-way max on inner reads
    __shared__ float Bs[16][68];
    const int t = threadIdx.x;
    const int m0 = blockIdx.y << 6;
    const int n0 = blockIdx.x << 6;
    const int lrow = t >> 2;        // 0..63 : tile row loaded by this thread
    const int lkb  = (t & 3) << 2;  // 0,4,8,12 : k-offset of its float4
    const int txc = t & 15;         // 16 col-groups
    const int tyr = t >> 4;         // 16 row-groups

    float acc[4][4];
#pragma unroll
    for (int i = 0; i < 4; ++i)
#pragma unroll
        for (int j = 0; j < 4; ++j) acc[i][j] = 0.f;

    const float* Ap = A + (size_t)(m0 + lrow) * 512 + lkb;
    const float* Wp = W + (size_t)(n0 + lrow) * 512 + lkb;

    for (int k0 = 0; k0 < 512; k0 += 16) {
        const float4 av = *(const float4*)(Ap + k0);
        const float4 bv = *(const float4*)(Wp + k0);
        __syncthreads();            // previous iteration's LDS reads done
        As[lkb + 0][lrow] = av.x; As[lkb + 1][lrow] = av.y;
        As[lkb + 2][lrow] = av.z; As[lkb + 3][lrow] = av.w;
        Bs[lkb + 0][lrow] = bv.x; Bs[lkb + 1][lrow] = bv.y;
        Bs[lkb + 2][lrow] = bv.z; Bs[lkb + 3][lrow] = bv.w;
        __syncthreads();
#pragma unroll
        for (int kk = 0; kk < 16; ++kk) {
            const float4 a = *(const float4*)&As[kk][tyr << 2];
            const float4 b = *(const float4*)&Bs[kk][txc << 2];
            const float ar[4] = {a.x, a.y, a.z, a.w};
            const float br[4] = {b.x, b.y, b.z, b.w};
#pragma unroll
            for (int i = 0; i < 4; ++i)
#pragma unroll
                for (int j = 0; j < 4; ++j)
                    acc[i][j] = fmaf(ar[i], br[j], acc[i][j]);
        }
    }

#pragma unroll
    for (int i = 0; i < 4; ++i) {
        const int m = m0 + (tyr << 2) + i;
        const int bb = m >> 11;        // batch
        const int ss = m & 2047;       // seq pos
#pragma unroll
        for (int j = 0; j < 4; ++j) {
            const int n = n0 + (txc << 2) + j;
            const float v = acc[i][j];
            if constexpr (MODE == 0) {
                const int h = n / 192;
                const int r = n - h * 192;
                const size_t rb = (size_t)(bb * H + h) * S + ss;
                if (r < 64)       o0[rb * 128 + r] = v;          // word q
                else if (r < 128) o1[rb * 128 + (r - 64)] = v;   // word k
                else              o2[rb * 64  + (r - 128)] = v;  // v
            } else if constexpr (MODE == 1) {
                const int h = n >> 7;
                const int r = n & 127;
                const size_t rb = (size_t)(bb * H + h) * S + ss;
                if (r < 64) o0[rb * 128 + 64 + r] = v;           // Uq
                else        o1[rb * 128 + 64 + (r - 64)] = v;    // Uk
            } else {
                o0[(size_t)m * 512 + n] = v;
            }
        }
    }
}

// ---------------------------------------------------------------------------
// Flash attention, fp32.  One block = one (b,h) x 64-query tile.
// Combined head dim 128 (word + positional), bias PE_r, scale 1/sqrt(128).
// 256 threads: tx=t&7 (8 col/dim groups), ty=t>>3 (32 row groups).
// Each thread: rows {ty, ty+32}; score cols {tx+8j}; output dims tx*8..tx*8+7.
// LDS: Qs[64][132] + KPs[32][132] (P[64][36] aliased) + Vs[32][68] = 59.4 KB
// ---------------------------------------------------------------------------
__global__ __launch_bounds__(256)
void attn_fp32(const float* __restrict__ Qp, const float* __restrict__ Kp,
               const float* __restrict__ Vp, const float* __restrict__ PEr,
               float* __restrict__ vals)
{
    __shared__ float Qs[64 * 132];
    __shared__ float KPs[32 * 132];   // K tile; after scores, reused as P[64][36]
    __shared__ float Vs[32 * 68];

    const int t  = threadIdx.x;
    const int tx = t & 7;
    const int ty = t >> 3;
    const int q0 = blockIdx.x << 6;
    const int h  = blockIdx.y;
    const int b  = blockIdx.z;
    const size_t bh = (size_t)(b * H + h);
    const float* Qg = Qp + bh * S * 128;
    const float* Kg = Kp + bh * S * 128;
    const float* Vg = Vp + bh * S * 64;
    const float* Pg = PEr + (size_t)h * S * S;

    // ---- load Q tile (once) ----
    {
        const int row = t >> 2;
        const int db  = (t & 3) << 2;
        const float* src = Qg + (size_t)(q0 + row) * 128 + db;
        float* dst = &Qs[row * 132 + db];
#pragma unroll
        for (int i = 0; i < 8; ++i)
            *(float4*)(dst + i * 16) = *(const float4*)(src + i * 16);
    }

    const int r0 = ty, r1 = ty + 32;
    float m_i[2] = {-1e30f, -1e30f};
    float l_i[2] = {0.f, 0.f};
    float o[2][8];
#pragma unroll
    for (int i = 0; i < 2; ++i)
#pragma unroll
        for (int j = 0; j < 8; ++j) o[i][j] = 0.f;

    const float scale = 0.0883883476483184f;   // 1/sqrt(2*hd) = 1/sqrt(128)

    for (int kt = 0; kt < 64; ++kt) {
        const int k0 = kt << 5;
        __syncthreads();   // previous tile's P/V reads done -> safe to overwrite

        // ---- load K tile [32][128] ----
        {
            const int row = t >> 3;
            const int db  = (t & 7) << 2;
            const float* src = Kg + (size_t)(k0 + row) * 128 + db;
            float* dst = &KPs[row * 132 + db];
#pragma unroll
            for (int i = 0; i < 4; ++i)
                *(float4*)(dst + i * 32) = *(const float4*)(src + i * 32);
        }
        // ---- load V tile [32][64] ----
        {
            const int row = t >> 3;
            const int db  = (t & 7) << 3;
            const float* src = Vg + (size_t)(k0 + row) * 64 + db;
            float* dst = &Vs[row * 68 + db];
            *(float4*)(dst)     = *(const float4*)(src);
            *(float4*)(dst + 4) = *(const float4*)(src + 4);
        }
        __syncthreads();

        // ---- scores: 2 rows x 4 cols per thread over d=128 ----
        float s[2][4] = {{0.f, 0.f, 0.f, 0.f}, {0.f, 0.f, 0.f, 0.f}};
#pragma unroll 4
        for (int d4 = 0; d4 < 128; d4 += 4) {
            const float4 qa = *(const float4*)&Qs[r0 * 132 + d4];
            const float4 qb = *(const float4*)&Qs[r1 * 132 + d4];
#pragma unroll
            for (int j = 0; j < 4; ++j) {
                const float4 kv = *(const float4*)&KPs[(tx + 8 * j) * 132 + d4];
                s[0][j] += qa.x * kv.x + qa.y * kv.y + qa.z * kv.z + qa.w * kv.w;
                s[1][j] += qb.x * kv.x + qb.y * kv.y + qb.z * kv.z + qb.w * kv.w;
            }
        }

        // ---- scale + PE_r bias ----
#pragma unroll
        for (int i = 0; i < 2; ++i) {
            const int qq = q0 + (i ? r1 : r0);
            const float* prow = Pg + (size_t)qq * S + k0 + tx;
#pragma unroll
            for (int j = 0; j < 4; ++j)
                s[i][j] = fmaf(s[i][j], scale, prow[8 * j]);
        }

        // ---- online softmax (8-lane tx-group reductions) ----
        float pv[2][4];
#pragma unroll
        for (int i = 0; i < 2; ++i) {
            float mx = fmaxf(fmaxf(s[i][0], s[i][1]), fmaxf(s[i][2], s[i][3]));
            mx = fmaxf(mx, __shfl_xor(mx, 1));
            mx = fmaxf(mx, __shfl_xor(mx, 2));
            mx = fmaxf(mx, __shfl_xor(mx, 4));
            const float mnew = fmaxf(m_i[i], mx);
            const float alpha = __expf(m_i[i] - mnew);
            float sum = 0.f;
#pragma unroll
            for (int j = 0; j < 4; ++j) {
                pv[i][j] = __expf(s[i][j] - mnew);
                sum += pv[i][j];
            }
            sum += __shfl_xor(sum, 1);
            sum += __shfl_xor(sum, 2);
            sum += __shfl_xor(sum, 4);
            l_i[i] = l_i[i] * alpha + sum;
            m_i[i] = mnew;
#pragma unroll
            for (int j = 0; j < 8; ++j) o[i][j] *= alpha;
        }

        __syncthreads();   // everyone done reading K -> reuse KPs as P[64][36]
        float* Ps = KPs;
#pragma unroll
        for (int i = 0; i < 2; ++i) {
            const int r = i ? r1 : r0;
#pragma unroll
            for (int j = 0; j < 4; ++j)
                Ps[r * 36 + tx + 8 * j] = pv[i][j];
        }
        __syncthreads();

        // ---- PV: o[2][8] += P[r][kk] * V[kk][tx*8 + jj] ----
#pragma unroll 4
        for (int kk = 0; kk < 32; ++kk) {
            const float p0 = Ps[r0 * 36 + kk];
            const float p1 = Ps[r1 * 36 + kk];
            const float4 v0 = *(const float4*)&Vs[kk * 68 + tx * 8];
            const float4 v1 = *(const float4*)&Vs[kk * 68 + tx * 8 + 4];
            o[0][0] += p0 * v0.x; o[0][1] += p0 * v0.y;
            o[0][2] += p0 * v0.z; o[0][3] += p0 * v0.w;
            o[0][4] += p0 * v1.x; o[0][5] += p0 * v1.y;
            o[0][6] += p0 * v1.z; o[0][7] += p0 * v1.w;
            o[1][0] += p1 * v0.x; o[1][1] += p1 * v0.y;
            o[1][2] += p1 * v0.z; o[1][3] += p1 * v0.w;
            o[1][4] += p1 * v1.x; o[1][5] += p1 * v1.y;
            o[1][6] += p1 * v1.z; o[1][7] += p1 * v1.w;
        }
    }

    // ---- epilogue: vals[b, s, h*64 + d] = o / l ----
#pragma unroll
    for (int i = 0; i < 2; ++i) {
        const int r = i ? r1 : r0;
        const float inv = 1.f / l_i[i];
        float* dst = vals + ((size_t)b * S + q0 + r) * 512 + h * 64 + tx * 8;
#pragma unroll
        for (int j = 0; j < 8; ++j) dst[j] = o[i][j] * inv;
    }
}

} // namespace

extern "C" void kernel_launch(void* const* d_in, const int* in_sizes, int n_in,
                              void* d_out, int out_size, void* d_ws, size_t ws_size,
                              hipStream_t stream)
{
    const float* x    = (const float*)d_in[0];   // [4,2048,512]
    const float* PE   = (const float*)d_in[1];   // [4,2048,512]
    const float* PEr  = (const float*)d_in[2];   // [8,2048,2048]
    const float* Wqkv = (const float*)d_in[3];   // [1536,512]
    const float* UqUk = (const float*)d_in[4];   // [1024,512]
    const float* Wo   = (const float*)d_in[5];   // [512,512]
    float* out = (float*)d_out;                  // [4,2048,512]

    // workspace: Q'[B,H,S,128] K'[B,H,S,128] V[B,H,S,64] vals[B,S,512] = 96 MB
    float* Qp   = (float*)d_ws;
    float* Kp   = Qp + (size_t)B * H * S * 128;
    float* Vp   = Kp + (size_t)B * H * S * 128;
    float* vals = Vp + (size_t)B * H * S * 64;

    const dim3 blk(256);
    gemm_bt<0><<<dim3(24, 128), blk, 0, stream>>>(x,    Wqkv, Qp, Kp, Vp);
    gemm_bt<1><<<dim3(16, 128), blk, 0, stream>>>(PE,   UqUk, Qp, Kp, nullptr);
    attn_fp32 <<<dim3(32, 8, 4), blk, 0, stream>>>(Qp, Kp, Vp, PEr, vals);
    gemm_bt<2><<<dim3(8, 128),  blk, 0, stream>>>(vals, Wo,   out, nullptr, nullptr);
}

// Round 7
// 403.727 us; speedup vs baseline: 4.0195x; 4.0195x over previous
//
#include <hip/hip_runtime.h>
#include <math.h>

namespace {

typedef __attribute__((ext_vector_type(8))) short bf16x8;
typedef __attribute__((ext_vector_type(4))) float f32x4;

constexpr int S = 2048;
constexpr int B = 4;
constexpr int H = 8;

__device__ __forceinline__ uint f2bf(float f) {
    union { float f; uint u; } v; v.f = f;
    return (v.u + 0x7fffu + ((v.u >> 16) & 1u)) >> 16;
}

__device__ __forceinline__ void gload_lds16(const void* g, void* l) {
    __builtin_amdgcn_global_load_lds(
        (const __attribute__((address_space(1))) void*)g,
        (__attribute__((address_space(3))) void*)l, 16, 0, 0);
}

// ---------------------------------------------------------------------------
// fp32 -> bf16 convert, 8 elems/thread, exact grids (n % 2048 == 0)
// ---------------------------------------------------------------------------
__global__ __launch_bounds__(256)
void cvt_f32_bf16(const float* __restrict__ in, ushort* __restrict__ out) {
    const size_t i = ((size_t)blockIdx.x * 256 + threadIdx.x) * 8;
    const float4 a = *(const float4*)(in + i);
    const float4 b = *(const float4*)(in + i + 4);
    uint4 r;
    r.x = f2bf(a.x) | (f2bf(a.y) << 16);
    r.y = f2bf(a.z) | (f2bf(a.w) << 16);
    r.z = f2bf(b.x) | (f2bf(b.y) << 16);
    r.w = f2bf(b.z) | (f2bf(b.w) << 16);
    *(uint4*)(out + i) = r;
}

// ---------------------------------------------------------------------------
// bf16 MFMA GEMM, swapped orientation: D[n][m] = sum_k Wt[n][k] * X[m][k].
// Tile 128(n) x 128(m), BK=32, 4 waves (2x2), 16x16x32 MFMA, 4x4 frags/wave.
// LDS chunk layout [c][row][8] -> all fragment reads are conflict-free b128.
// MODE 0: Wqkv -> Q'(d 0..63), K'(d 0..63), Vt    (n: h=n/192, r=n%192)
// MODE 1: UqUk -> Q'(d 64..127), K'(d 64..127)    (n: h=n>>7,  r=n&127)
// MODE 2: Wo   -> out fp32 row-major [m][n]
// R5 FIX: MODE 1 Uk branch wrote K' features (rr-64) in [0,64) -- clobbering
// word-k and leaving K'[64..128) poisoned.  Correct offset is rr (=64+(rr-64)).
// This one-char bug explains the bit-identical absmax across r1-r4.
// ---------------------------------------------------------------------------
template<int MODE>
__global__ __launch_bounds__(256)
void gemm_bf16(const ushort* __restrict__ Wt, const ushort* __restrict__ X,
               ushort* __restrict__ o0, ushort* __restrict__ o1,
               ushort* __restrict__ o2, float* __restrict__ of)
{
    __shared__ ushort Wc[4 * 128 * 8];   // 8 KB  [c=k/8][nrow][8]
    __shared__ ushort Xc[4 * 128 * 8];   // 8 KB  [c=k/8][mrow][8]
    const int t = threadIdx.x;
    const int w = t >> 6, l = t & 63;
    const int lc = l >> 4, ln = l & 15;
    const int n0 = blockIdx.x * 128, m0 = blockIdx.y * 128;
    const int nw = (w & 1) * 64, mw = (w >> 1) * 64;

    f32x4 acc[4][4];
#pragma unroll
    for (int i = 0; i < 4; ++i)
#pragma unroll
        for (int j = 0; j < 4; ++j) acc[i][j] = (f32x4)0.f;

    for (int k0 = 0; k0 < 512; k0 += 32) {
        __syncthreads();
        // 16 staging instrs (8 W, 8 X); wave w issues ids [4w, 4w+4)
#pragma unroll
        for (int ii = 0; ii < 4; ++ii) {
            const int id = w * 4 + ii;
            const int c = (id >> 1) & 3;
            const int half = id & 1;
            const int row = half * 64 + l;
            if (id < 8)
                gload_lds16(Wt + (size_t)(n0 + row) * 512 + k0 + 8 * c,
                            Wc + c * 1024 + half * 512);
            else
                gload_lds16(X + (size_t)(m0 + row) * 512 + k0 + 8 * c,
                            Xc + c * 1024 + half * 512);
        }
        __syncthreads();

        bf16x8 af[4], bf[4];
#pragma unroll
        for (int fn = 0; fn < 4; ++fn)
            af[fn] = *(const bf16x8*)(Wc + lc * 1024 + (nw + 16 * fn + ln) * 8);
#pragma unroll
        for (int fm = 0; fm < 4; ++fm)
            bf[fm] = *(const bf16x8*)(Xc + lc * 1024 + (mw + 16 * fm + ln) * 8);
#pragma unroll
        for (int fn = 0; fn < 4; ++fn)
#pragma unroll
            for (int fm = 0; fm < 4; ++fm)
                acc[fn][fm] = __builtin_amdgcn_mfma_f32_16x16x32_bf16(
                    af[fn], bf[fm], acc[fn][fm], 0, 0, 0);
    }

    // epilogue: lane holds, per (fn,fm), 4 consecutive n at fixed m
#pragma unroll
    for (int fn = 0; fn < 4; ++fn) {
        const int nq = n0 + nw + 16 * fn + 4 * lc;   // n base (multiple of 4)
#pragma unroll
        for (int fm = 0; fm < 4; ++fm) {
            const int m = m0 + mw + 16 * fm + ln;
            const int bb = m >> 11;        // batch
            const int ss = m & 2047;       // seq pos
            const f32x4 a = acc[fn][fm];
            if constexpr (MODE == 2) {
                *(f32x4*)(of + (size_t)m * 512 + nq) = a;
            } else {
                int hh, rr;
                if constexpr (MODE == 0) { hh = nq / 192; rr = nq - hh * 192; }
                else                     { hh = nq >> 7;  rr = nq & 127; }
                const size_t bh = (size_t)(bb * H + hh);
                const uint2 pk = { f2bf(a.x) | (f2bf(a.y) << 16),
                                   f2bf(a.z) | (f2bf(a.w) << 16) };
                if constexpr (MODE == 0) {
                    if (rr < 64)
                        *(uint2*)(o0 + (bh * S + ss) * 128 + rr) = pk;          // word q -> Q'[0..64)
                    else if (rr < 128)
                        *(uint2*)(o1 + (bh * S + ss) * 128 + (rr - 64)) = pk;   // word k -> K'[0..64)
                    else {
                        const int d0 = rr - 128;
                        o2[(bh * 64 + d0 + 0) * S + ss] = (ushort)f2bf(a.x);
                        o2[(bh * 64 + d0 + 1) * S + ss] = (ushort)f2bf(a.y);
                        o2[(bh * 64 + d0 + 2) * S + ss] = (ushort)f2bf(a.z);
                        o2[(bh * 64 + d0 + 3) * S + ss] = (ushort)f2bf(a.w);
                    }
                } else {
                    if (rr < 64)
                        *(uint2*)(o0 + (bh * S + ss) * 128 + 64 + rr) = pk;     // Uq -> Q'[64..128)
                    else
                        *(uint2*)(o1 + (bh * S + ss) * 128 + rr) = pk;          // Uk -> K'[64..128)  (FIXED)
                }
            }
        }
    }
}

// ---------------------------------------------------------------------------
// Flash attention, bf16 MFMA.  One block = (q-tile 128, b, h); 4 waves.
// Computes S^T = K.Q^T (PE_r bias float4-contiguous per lane; softmax axis
// lane-local + 2 shfls), then O^T = Vt.P^T.  Q frags in registers.  All LDS
// in [c][row][8] chunks (conflict-free b128).  KTILE=64; 32 q-cols/wave.
// ---------------------------------------------------------------------------
__global__ __launch_bounds__(256)
void attn_bf16(const ushort* __restrict__ Qp, const ushort* __restrict__ Kp,
               const ushort* __restrict__ Vt, const float* __restrict__ PEr,
               ushort* __restrict__ vals)
{
    __shared__ ushort Kc[16 * 64 * 8];   // 16 KB  [c=d/8][krow][8]
    __shared__ ushort Vc[8 * 64 * 8];    //  8 KB  [c=k/8][drow][8]
    __shared__ ushort Pt[8 * 128 * 8];   // 16 KB  [c=k/8][q][8]
    const int t = threadIdx.x, w = t >> 6, l = t & 63;
    const int lc = l >> 4, ln = l & 15;
    const int q0 = blockIdx.x * 128;
    const int b = blockIdx.y, h = blockIdx.z;
    const size_t bh = (size_t)(b * H + h);
    const ushort* Qg = Qp + bh * S * 128;
    const ushort* Kg = Kp + bh * S * 128;
    const ushort* Vg = Vt + bh * 64 * S;
    const float*  Pg = PEr + (size_t)h * S * S;
    const float scale = 0.08838834764831845f;   // 1/sqrt(2*64)

    // Q fragments (B-operand), registers, fixed for whole kernel
    const int qrow[2] = { q0 + 32 * w + ln, q0 + 32 * w + 16 + ln };
    bf16x8 qf[2][4];
#pragma unroll
    for (int fq = 0; fq < 2; ++fq)
#pragma unroll
        for (int kk = 0; kk < 4; ++kk)
            qf[fq][kk] = *(const bf16x8*)(Qg + (size_t)qrow[fq] * 128 + 32 * kk + 8 * lc);

    f32x4 oacc[4][2];
#pragma unroll
    for (int fd = 0; fd < 4; ++fd)
#pragma unroll
        for (int fq = 0; fq < 2; ++fq) oacc[fd][fq] = (f32x4)0.f;
    float m_i[2] = { -1e30f, -1e30f }, l_i[2] = { 0.f, 0.f };

    for (int kt = 0; kt < 32; ++kt) {
        const int k0 = kt * 64;
        __syncthreads();   // all waves done reading Kc/Vc of prev tile

        // stage K (16 instrs) + Vt (8 instrs); wave w: K c=[4w,4w+4), V c=[2w,2w+2)
#pragma unroll
        for (int ii = 0; ii < 4; ++ii) {
            const int c = 4 * w + ii;
            gload_lds16(Kg + (size_t)(k0 + l) * 128 + 8 * c, Kc + c * 512);
        }
#pragma unroll
        for (int ii = 0; ii < 2; ++ii) {
            const int c = 2 * w + ii;
            gload_lds16(Vg + (size_t)l * S + k0 + 8 * c, Vc + c * 512);
        }
        // bias: PE_r fp32, 4 consecutive k per lane -> float4
        f32x4 bias[4][2];
#pragma unroll
        for (int fk = 0; fk < 4; ++fk)
#pragma unroll
            for (int fq = 0; fq < 2; ++fq)
                bias[fk][fq] = *(const f32x4*)(Pg + (size_t)qrow[fq] * S + k0 + 16 * fk + 4 * lc);
        __syncthreads();   // staging (and bias) complete

        // S^T = K . Q^T  : rows k (KTILE=64 -> fk 0..3), cols q (wave's 32)
        f32x4 s[4][2];
#pragma unroll
        for (int fk = 0; fk < 4; ++fk)
#pragma unroll
            for (int fq = 0; fq < 2; ++fq) s[fk][fq] = (f32x4)0.f;
#pragma unroll
        for (int kk = 0; kk < 4; ++kk) {
            bf16x8 kf[4];
#pragma unroll
            for (int fk = 0; fk < 4; ++fk)
                kf[fk] = *(const bf16x8*)(Kc + (4 * kk + lc) * 512 + (16 * fk + ln) * 8);
#pragma unroll
            for (int fk = 0; fk < 4; ++fk)
#pragma unroll
                for (int fq = 0; fq < 2; ++fq)
                    s[fk][fq] = __builtin_amdgcn_mfma_f32_16x16x32_bf16(
                        kf[fk], qf[fq][kk], s[fk][fq], 0, 0, 0);
        }

        // scale + bias + online softmax (per q-col: 16 in-lane + shfl 16,32)
#pragma unroll
        for (int fq = 0; fq < 2; ++fq) {
            float mx = -1e30f;
#pragma unroll
            for (int fk = 0; fk < 4; ++fk) {
                s[fk][fq].x = fmaf(s[fk][fq].x, scale, bias[fk][fq].x);
                s[fk][fq].y = fmaf(s[fk][fq].y, scale, bias[fk][fq].y);
                s[fk][fq].z = fmaf(s[fk][fq].z, scale, bias[fk][fq].z);
                s[fk][fq].w = fmaf(s[fk][fq].w, scale, bias[fk][fq].w);
                mx = fmaxf(mx, fmaxf(fmaxf(s[fk][fq].x, s[fk][fq].y),
                                     fmaxf(s[fk][fq].z, s[fk][fq].w)));
            }
            mx = fmaxf(mx, __shfl_xor(mx, 16));
            mx = fmaxf(mx, __shfl_xor(mx, 32));
            const float mnew = fmaxf(m_i[fq], mx);
            const float alpha = __expf(m_i[fq] - mnew);
            float rs = 0.f;
#pragma unroll
            for (int fk = 0; fk < 4; ++fk) {
                s[fk][fq].x = __expf(s[fk][fq].x - mnew);
                s[fk][fq].y = __expf(s[fk][fq].y - mnew);
                s[fk][fq].z = __expf(s[fk][fq].z - mnew);
                s[fk][fq].w = __expf(s[fk][fq].w - mnew);
                rs += s[fk][fq].x + s[fk][fq].y + s[fk][fq].z + s[fk][fq].w;
            }
            rs += __shfl_xor(rs, 16);
            rs += __shfl_xor(rs, 32);
            l_i[fq] = l_i[fq] * alpha + rs;
            m_i[fq] = mnew;
#pragma unroll
            for (int fd = 0; fd < 4; ++fd) oacc[fd][fq] *= alpha;
        }

        // write P^T (bf16) to LDS: 4 consecutive k per lane -> one b64 write
#pragma unroll
        for (int fk = 0; fk < 4; ++fk)
#pragma unroll
            for (int fq = 0; fq < 2; ++fq) {
                const uint2 pk = { f2bf(s[fk][fq].x) | (f2bf(s[fk][fq].y) << 16),
                                   f2bf(s[fk][fq].z) | (f2bf(s[fk][fq].w) << 16) };
                *(uint2*)(Pt + (2 * fk + (lc >> 1)) * 1024 +
                          (32 * w + 16 * fq + ln) * 8 + (lc & 1) * 4) = pk;
            }
        __syncthreads();   // order Pt writes before Pt reads

        // O^T += Vt . P^T
#pragma unroll
        for (int kk2 = 0; kk2 < 2; ++kk2) {
            bf16x8 vf[4], pf[2];
#pragma unroll
            for (int fd = 0; fd < 4; ++fd)
                vf[fd] = *(const bf16x8*)(Vc + (4 * kk2 + lc) * 512 + (16 * fd + ln) * 8);
#pragma unroll
            for (int fq = 0; fq < 2; ++fq)
                pf[fq] = *(const bf16x8*)(Pt + (4 * kk2 + lc) * 1024 +
                                          (32 * w + 16 * fq + ln) * 8);
#pragma unroll
            for (int fd = 0; fd < 4; ++fd)
#pragma unroll
                for (int fq = 0; fq < 2; ++fq)
                    oacc[fd][fq] = __builtin_amdgcn_mfma_f32_16x16x32_bf16(
                        vf[fd], pf[fq], oacc[fd][fq], 0, 0, 0);
        }
    }

    // epilogue: vals[b][q][h*64 + d], 4 consecutive d per lane -> 8B stores
#pragma unroll
    for (int fq = 0; fq < 2; ++fq) {
        const float inv = 1.f / l_i[fq];
#pragma unroll
        for (int fd = 0; fd < 4; ++fd) {
            const f32x4 o = oacc[fd][fq];
            const uint2 pk = { f2bf(o.x * inv) | (f2bf(o.y * inv) << 16),
                               f2bf(o.z * inv) | (f2bf(o.w * inv) << 16) };
            *(uint2*)(vals + ((size_t)b * S + qrow[fq]) * 512 + h * 64 +
                      16 * fd + 4 * lc) = pk;
        }
    }
}

} // namespace

extern "C" void kernel_launch(void* const* d_in, const int* in_sizes, int n_in,
                              void* d_out, int out_size, void* d_ws, size_t ws_size,
                              hipStream_t stream)
{
    const float* x    = (const float*)d_in[0];   // [4,2048,512]
    const float* PE   = (const float*)d_in[1];   // [4,2048,512]
    const float* PEr  = (const float*)d_in[2];   // [8,2048,2048] fp32, read direct
    const float* Wqkv = (const float*)d_in[3];   // [1536,512]
    const float* UqUk = (const float*)d_in[4];   // [1024,512]
    const float* Wo   = (const float*)d_in[5];   // [512,512]
    float* out = (float*)d_out;                  // [4,2048,512]

    // bf16 workspace (ushort elements), ~70 MB total
    ushort* xb   = (ushort*)d_ws;
    ushort* peb  = xb   + 4194304;
    ushort* wqkb = peb  + 4194304;
    ushort* uqkb = wqkb + 786432;
    ushort* wob  = uqkb + 524288;
    ushort* Qp   = wob  + 262144;            // [32][2048][128]
    ushort* Kp   = Qp   + 8388608;           // [32][2048][128]
    ushort* Vt   = Kp   + 8388608;           // [32][64][2048]
    ushort* vals = Vt   + 4194304;           // [8192][512]

    const dim3 blk(256);
    cvt_f32_bf16<<<2048, blk, 0, stream>>>(x,    xb);
    cvt_f32_bf16<<<2048, blk, 0, stream>>>(PE,   peb);
    cvt_f32_bf16<<<384,  blk, 0, stream>>>(Wqkv, wqkb);
    cvt_f32_bf16<<<256,  blk, 0, stream>>>(UqUk, uqkb);
    cvt_f32_bf16<<<128,  blk, 0, stream>>>(Wo,   wob);

    gemm_bf16<0><<<dim3(12, 64), blk, 0, stream>>>(wqkb, xb,   Qp, Kp, Vt, nullptr);
    gemm_bf16<1><<<dim3(8,  64), blk, 0, stream>>>(uqkb, peb,  Qp, Kp, nullptr, nullptr);
    attn_bf16   <<<dim3(16, 4, 8), blk, 0, stream>>>(Qp, Kp, Vt, PEr, vals);
    gemm_bf16<2><<<dim3(4,  64), blk, 0, stream>>>(wob, vals, nullptr, nullptr, nullptr, out);
}